// Round 4
// baseline (326.087 us; speedup 1.0000x reference)
//
#include <hip/hip_runtime.h>

#define IDIM   256
#define HDIM   64
#define BATCH  1024
#define NITEMS 200
#define NCOLS  (IDIM * HDIM)   // 16384

typedef __bf16 bf16x8 __attribute__((ext_vector_type(8)));
typedef float  f32x4  __attribute__((ext_vector_type(4)));

__device__ __forceinline__ unsigned short f2bf(float f) {
    unsigned int u = __float_as_uint(f);
    u += 0x7FFFu + ((u >> 16) & 1u);   // round-to-nearest-even
    return (unsigned short)(u >> 16);
}

// fast tanh: 1 - 2/(e^{2x}+1); v_exp+v_rcp, saturates correctly (rcp(inf)=0)
__device__ __forceinline__ float fast_tanh(float x) {
    float e2 = __expf(2.0f * x);
    return 1.0f - 2.0f * __builtin_amdgcn_rcpf(e2 + 1.0f);
}

// 16-lane (DPP row) rotate-add: ctrl = 0x121/0x122/0x124/0x128 (row_ror:1/2/4/8).
// After all four, every one of the 16 lanes holds the row sum. VALU pipe.
template <int CTRL>
__device__ __forceinline__ float row_ror_add(float x) {
    return x + __int_as_float(__builtin_amdgcn_update_dpp(
        0, __float_as_int(x), CTRL, 0xF, 0xF, false));
}
#define ROW_REDUCE16(d)                 \
    d = row_ror_add<0x121>(d);          \
    d = row_ror_add<0x122>(d);          \
    d = row_ror_add<0x124>(d);          \
    d = row_ror_add<0x128>(d);

// async global->LDS, 16B per lane; LDS dest must be linear in lane order
#define GLOAD_LDS16(g, l) __builtin_amdgcn_global_load_lds(                 \
    (const __attribute__((address_space(1))) void*)(g),                     \
    (__attribute__((address_space(3))) void*)(l), 16, 0, 0)

// ---- fused prep: blocks [0,4096) transpose Wq f32[k][n] -> Bt bf16[n][k];
//      blocks [4096,4352) convert query f32 -> bf16 (layout unchanged) ----
__global__ __launch_bounds__(256) void k_prep(const float* __restrict__ q,
                                              const float* __restrict__ Wq,
                                              unsigned short* __restrict__ Aq,
                                              unsigned short* __restrict__ Bt) {
    __shared__ float tile[32][33];
    int blk = blockIdx.x;
    int tid = threadIdx.x;
    if (blk >= 4096) {                       // conv branch (block-uniform)
        int idx = (blk - 4096) * 256 + tid;  // 65536 float4s
        float4 f = ((const float4*)q)[idx];
        ushort4 o;
        o.x = f2bf(f.x); o.y = f2bf(f.y); o.z = f2bf(f.z); o.w = f2bf(f.w);
        ((ushort4*)Aq)[idx] = o;
        return;
    }
    int n0 = (blk & 511) * 32;               // 512 n-tiles
    int k0 = (blk >> 9) * 32;                // 8 k-tiles
    // float4-vectorized tile load: thread covers row tid>>3, 4 cols
    int ty4 = tid >> 3;                      // 0..31 (k within tile)
    int tx4 = (tid & 7) * 4;                 // 0,4,...,28 (n within tile)
    float4 f = *(const float4*)&Wq[(size_t)(k0 + ty4) * NCOLS + n0 + tx4];
    tile[ty4][tx4 + 0] = f.x; tile[ty4][tx4 + 1] = f.y;
    tile[ty4][tx4 + 2] = f.z; tile[ty4][tx4 + 3] = f.w;
    __syncthreads();
    // transposed write, ushort4 per store (8 B/lane), single pass
    int nr = tid >> 3;                       // 0..31 (n row of Bt)
    int kc = (tid & 7) * 4;                  // 0,4,...,28 (k chunk)
    ushort4 o;
    o.x = f2bf(tile[kc + 0][nr]);
    o.y = f2bf(tile[kc + 1][nr]);
    o.z = f2bf(tile[kc + 2][nr]);
    o.w = f2bf(tile[kc + 3][nr]);
    *(ushort4*)&Bt[(size_t)(n0 + nr) * IDIM + k0 + kc] = o;
}

// ---- GEMM: P = Aq(1024x256) @ Wq(256x16384), double-buffered LDS 128x128
//      tile (stage next BEFORE compute current, one barrier per K-step),
//      fused bias+tanh+W_r reduce -> V (1024x256 f32).
//      __launch_bounds__(256,4): 4 waves/EU -> VGPR<=128 -> 4 blocks/CU
//      (grid 1024 = exactly one full residency round). nt-outer fragment
//      loop keeps live frags at a[4]+b[1] = 20 VGPR so 128 is spill-free.
__global__ __launch_bounds__(256, 4) void k_gemm_v(const unsigned short* __restrict__ Aq,
                                                   const unsigned short* __restrict__ Bt,
                                                   const float* __restrict__ bq,
                                                   const float* __restrict__ Wr,
                                                   float* __restrict__ V) {
    __shared__ __align__(16) unsigned short As[2][128 * 32];   // 2 x 8 KB
    __shared__ __align__(16) unsigned short Bs[2][128 * 32];   // 2 x 8 KB
    int tid  = threadIdx.x;
    int w    = tid >> 6;
    int lane = tid & 63;
    int l16  = lane & 15;
    int quad = lane >> 4;
    int blk  = blockIdx.x;
    int bn   = blk & 127;                    // 128 n-blocks of 128 cols
    int bm   = blk >> 7;                     // 8 m-blocks of 128 rows

    int m_off  = (w & 1) * 64;
    int n_off  = (w >> 1) * 64;
    int n_base = bn * 128 + n_off;           // multiple of 64
    int icol   = bn * 2 + (w >> 1);          // output column of V, 0..255

    // staging addresses: thread t covers row (t>>2), 16B chunk (t&3); 2 halves
    const unsigned short* Ag = Aq + (size_t)(bm * 128 + (tid >> 2)) * IDIM + (tid & 3) * 8;
    const unsigned short* Bg = Bt + (size_t)(bn * 128 + (tid >> 2)) * IDIM + (tid & 3) * 8;

#define STAGE(buf, kk) do {                                                \
        GLOAD_LDS16(Ag + (kk) * 32,             &As[buf][tid * 8]);        \
        GLOAD_LDS16(Ag + 64 * IDIM + (kk) * 32, &As[buf][2048 + tid * 8]); \
        GLOAD_LDS16(Bg + (kk) * 32,             &Bs[buf][tid * 8]);        \
        GLOAD_LDS16(Bg + 64 * IDIM + (kk) * 32, &Bs[buf][2048 + tid * 8]); \
    } while (0)

    // epilogue operands loaded early (L2-hot, independent of the K-loop)
    float bv[4], wr[4];
#pragma unroll
    for (int nt = 0; nt < 4; nt++) {
        int nl = nt * 16 + l16;
        bv[nt] = bq[n_base + nl];
        wr[nt] = Wr[nl];
    }

    f32x4 acc[4][4] = {};
    STAGE(0, 0);
    __syncthreads();                         // buf0 ready
#pragma unroll
    for (int kk = 0; kk < 8; kk++) {
        int cur = kk & 1;
        if (kk < 7) STAGE(cur ^ 1, kk + 1);  // issue-early: latency hides under MFMA
        const unsigned short* Asp = &As[cur][(m_off + l16) * 32 + quad * 8];
        const unsigned short* Bsp = &Bs[cur][(n_off + l16) * 32 + quad * 8];
        bf16x8 a[4];
#pragma unroll
        for (int t = 0; t < 4; t++) a[t] = *(const bf16x8*)(Asp + t * 16 * 32);
#pragma unroll
        for (int nt = 0; nt < 4; nt++) {
            bf16x8 b = *(const bf16x8*)(Bsp + nt * 16 * 32);
#pragma unroll
            for (int mt = 0; mt < 4; mt++)
                acc[mt][nt] = __builtin_amdgcn_mfma_f32_16x16x32_bf16(a[mt], b, acc[mt][nt], 0, 0, 0);
        }
        __syncthreads();                     // drains vmcnt (next buf ready) + read-before-overwrite safety
    }
#undef STAGE

    int i = icol;
#pragma unroll
    for (int mt = 0; mt < 4; mt++) {
#pragma unroll
        for (int reg = 0; reg < 4; reg++) {
            float s = 0.0f;
#pragma unroll
            for (int nt = 0; nt < 4; nt++) {
                float c = acc[mt][nt][reg] + bv[nt];
                s += fast_tanh(c) * wr[nt];
            }
            ROW_REDUCE16(s);                 // DPP rotate-reduce over l16
            if (l16 == 0) {
                int m = bm * 128 + m_off + mt * 16 + quad * 4 + reg;
                V[m * IDIM + i] = s;
            }
        }
    }
}

// ---- fused score -> exp -> weighted accumulate, single pass over item ----
// one item per quad (16 lanes), 2 in flight per quad, 8 per wave.
// f32x4 ext-vector math so SLP can emit v_pk_fma_f32 (halves VALU FMA count).
__global__ __launch_bounds__(256) void k_score(const float* __restrict__ item,
                                               const float* __restrict__ V,
                                               float* __restrict__ out) {
    __shared__ float lacc[16][IDIM];   // 16 KB partials
    __shared__ float lS[16];
    int b    = blockIdx.x;
    int tid  = threadIdx.x;
    int wid  = tid >> 6;
    int lane = tid & 63;
    int l16  = lane & 15;
    int quad = lane >> 4;

    const f32x4* itemB = (const f32x4*)(item + (size_t)b * NITEMS * IDIM);
    const f32x4* Vb    = (const f32x4*)(V + (size_t)b * IDIM);

    f32x4 v[4];
#pragma unroll
    for (int c = 0; c < 4; c++) v[c] = Vb[l16 + 16 * c];

    f32x4 acc[4] = {};
    float S = 0.f;

    for (int chunk = wid; chunk < 25; chunk += 4) {
        int r0 = chunk * 8 + quad;       // item for x0
        int r1 = r0 + 4;                 // item for x1 (max 199)
        f32x4 x0[4], x1[4];
#pragma unroll
        for (int c = 0; c < 4; c++) x0[c] = itemB[(size_t)r0 * 64 + l16 + 16 * c];
#pragma unroll
        for (int c = 0; c < 4; c++) x1[c] = itemB[(size_t)r1 * 64 + l16 + 16 * c];

        f32x4 p0 = x0[0] * v[0];
        f32x4 p1 = x1[0] * v[0];
#pragma unroll
        for (int c = 1; c < 4; c++) {
            p0 += x0[c] * v[c];
            p1 += x1[c] * v[c];
        }
        float d0 = (p0[0] + p0[1]) + (p0[2] + p0[3]);
        float d1 = (p1[0] + p1[1]) + (p1[2] + p1[3]);
        // 16-lane reduce on the VALU pipe (DPP)
        ROW_REDUCE16(d0);
        ROW_REDUCE16(d1);
        float e0 = __expf(d0);
        float e1 = __expf(d1);
        S += e0 + e1;
#pragma unroll
        for (int c = 0; c < 4; c++)
            acc[c] += x0[c] * e0 + x1[c] * e1;
    }

    int row = wid * 4 + quad;            // 16 partial rows
#pragma unroll
    for (int c = 0; c < 4; c++)
        ((f32x4*)&lacc[row][0])[l16 + 16 * c] = acc[c];
    if (l16 == 0) lS[row] = S;
    __syncthreads();

    float s = 0.f;
#pragma unroll
    for (int i = 0; i < 16; i++) s += lacc[i][tid];
    float Stot = 0.f;
#pragma unroll
    for (int i = 0; i < 16; i++) Stot += lS[i];
    out[(size_t)b * IDIM + tid] = s / (1.0f + Stot);
}

extern "C" void kernel_launch(void* const* d_in, const int* in_sizes, int n_in,
                              void* d_out, int out_size, void* d_ws, size_t ws_size,
                              hipStream_t stream) {
    const float* item  = (const float*)d_in[0];
    const float* query = (const float*)d_in[1];
    const float* Wq    = (const float*)d_in[2];
    const float* bq    = (const float*)d_in[3];
    const float* Wr    = (const float*)d_in[4];
    float* out = (float*)d_out;

    char* ws = (char*)d_ws;
    unsigned short* Aq = (unsigned short*)ws;                          // 512 KB
    unsigned short* Bt = (unsigned short*)(ws + (512 << 10));          // 8 MB
    float*          V  = (float*)(ws + (512 << 10) + (8 << 20));       // 1 MB

    k_prep  <<<4352, 256, 0, stream>>>(query, Wq, Aq, Bt);
    k_gemm_v<<<1024, 256, 0, stream>>>(Aq, Bt, bq, Wr, V);
    k_score <<<1024, 256, 0, stream>>>(item, V, out);
}